// Round 13
// baseline (216.974 us; speedup 1.0000x reference)
//
#include <hip/hip_runtime.h>

// CapsuleLayer dynamic routing, MI355X. R16: W-in-registers, accumulate-in-LDS.
//  - R3..R15 invariant: W-in-LDS makes every wave re-read the full 32KB tile
//    per i (256KB LDS reads/CU-iter) inside a 2-barrier stage chain; all
//    scheduling variants land 42-46us/sweep, VALUBusy<=26%.
//  - R16 inverts: wave w holds W[ig*4+w] entirely in VGPRs (wr0/wr1[16]
//    float4 = 128 regs, 32 coalesced dwordx4 loads, NO LDS staging, NO stage
//    barriers). The i-sum lives in a 64KB LDS accumulator pre[b][o].
//  - 32 b-steps; wave w handles b=(8w+s)&31: distinct b per wave per step;
//    collision needs >=8-step skew; s_barrier every 4 steps bounds skew<=3
//    -> race-free LDS read-modify-write, no atomics.
//  - xs (wave-uniform s_load) and act (vector load) prefetched 1 step ahead
//    into parity-indexed buffers (static indices, rule #20).
//  - Round-2 fold: act = act0+act1 precomputed by round-1 reduce (R14's
//    verified outsum path, absmax 3e-8).
//
// Lane layout (R13-proven): lane l owns d=l>>1, h=l&1, o = d*16+h*8+j.
// h-combine: shfl_xor(1); softmax over 32 d: shfl_xor {2,4,8,16,32}
// (distances touch bits 1-5 only -> sums one lane per d).
// pre[] layout: float idx = b*512 + q*256 + lane*4 (q = j>>2):
// both RMW f4 accesses are lane*16B within a 1KB plane -> conflict-free.

#define B_  32
#define I_  2048
#define K_  16
#define O_  512
#define NG_ 512   // partial leading dim = #blocks
#define IC_ 4     // i's per block (= waves)

template<int PASS>
__global__ __launch_bounds__(256, 2)
void sweep_kernel(const float* __restrict__ x, const float* __restrict__ W,
                  const float* __restrict__ act_g, float* __restrict__ partial)
{
    const int tid  = threadIdx.x;
    const int lane = tid & 63;
    const int wave = tid >> 6;              // 0..3
    const int ig   = blockIdx.x;            // 0..511
    const int wv   = __builtin_amdgcn_readfirstlane(wave);
    const int i    = ig * IC_ + wv;         // wave's capsule
    const int d    = lane >> 1;
    const int h    = lane & 1;
    const int obase = d * 16 + h * 8;       // lane's first o

    __shared__ float pre[B_ * O_];          // 64 KB accumulator

    // zero the accumulator
    #pragma unroll
    for (int r = 0; r < 16; ++r)
        ((float4*)pre)[tid + 256 * r] = make_float4(0.f, 0.f, 0.f, 0.f);

    // W[i] into registers: lane's 8-o column, 2 float4 per k (coalesced)
    float4 wr0[K_], wr1[K_];
    {
        const float* Wb = W + (size_t)i * (K_ * O_) + obase;
        #pragma unroll
        for (int k = 0; k < K_; ++k) {
            wr0[k] = *(const float4*)(Wb + k * O_);
            wr1[k] = *(const float4*)(Wb + k * O_ + 4);
        }
    }

    __syncthreads();                        // pre[] zeroed

    // parity-buffered prefetch state (static first index everywhere)
    float xsb[2][16];
    float ab[2][8];
    {
        const int b0 = (8 * wv) & 31;
        const float4* xp = (const float4*)(x + ((size_t)b0 * I_ + i) * K_);
        #pragma unroll
        for (int q = 0; q < 4; ++q) {
            const float4 v = xp[q];
            xsb[0][4*q+0]=v.x; xsb[0][4*q+1]=v.y; xsb[0][4*q+2]=v.z; xsb[0][4*q+3]=v.w;
        }
        if (PASS >= 1) {
            const float4* ap = (const float4*)(act_g + b0 * O_ + obase);
            const float4 a0 = ap[0], a1 = ap[1];
            ab[0][0]=a0.x; ab[0][1]=a0.y; ab[0][2]=a0.z; ab[0][3]=a0.w;
            ab[0][4]=a1.x; ab[0][5]=a1.y; ab[0][6]=a1.z; ab[0][7]=a1.w;
        }
    }

    #pragma unroll 1
    for (int so = 0; so < 8; ++so) {
        #pragma unroll
        for (int si = 0; si < 4; ++si) {
            const int s = so * 4 + si;
            const int b = (8 * wv + s) & 31;

            // prefetch step s+1 (s=31 wraps to b(0): harmless in-bounds load)
            {
                const int bn = (8 * wv + s + 1) & 31;
                const float4* xp = (const float4*)(x + ((size_t)bn * I_ + i) * K_);
                #pragma unroll
                for (int q = 0; q < 4; ++q) {
                    const float4 v = xp[q];
                    xsb[(si+1)&1][4*q+0]=v.x; xsb[(si+1)&1][4*q+1]=v.y;
                    xsb[(si+1)&1][4*q+2]=v.z; xsb[(si+1)&1][4*q+3]=v.w;
                }
                if (PASS >= 1) {
                    const float4* ap = (const float4*)(act_g + bn * O_ + obase);
                    const float4 a0 = ap[0], a1 = ap[1];
                    ab[(si+1)&1][0]=a0.x; ab[(si+1)&1][1]=a0.y;
                    ab[(si+1)&1][2]=a0.z; ab[(si+1)&1][3]=a0.w;
                    ab[(si+1)&1][4]=a1.x; ab[(si+1)&1][5]=a1.y;
                    ab[(si+1)&1][6]=a1.z; ab[(si+1)&1][7]=a1.w;
                }
            }

            // V[j] = sum_k x[b,i,k] * W[i,k,obase+j]  (128 FMA, all regs)
            float V[8];
            #pragma unroll
            for (int j = 0; j < 8; ++j) V[j] = 0.f;
            #pragma unroll
            for (int k = 0; k < K_; ++k) {
                const float xk = xsb[si & 1][k];
                V[0] = fmaf(xk, wr0[k].x, V[0]);
                V[1] = fmaf(xk, wr0[k].y, V[1]);
                V[2] = fmaf(xk, wr0[k].z, V[2]);
                V[3] = fmaf(xk, wr0[k].w, V[3]);
                V[4] = fmaf(xk, wr1[k].x, V[4]);
                V[5] = fmaf(xk, wr1[k].y, V[5]);
                V[6] = fmaf(xk, wr1[k].z, V[6]);
                V[7] = fmaf(xk, wr1[k].w, V[7]);
            }

            float rV[8];
            if (PASS == 0) {
                #pragma unroll
                for (int j = 0; j < 8; ++j) rV[j] = V[j];
            } else {
                float p0 = 0.f;
                #pragma unroll
                for (int j = 0; j < 8; ++j) p0 = fmaf(V[j], ab[si & 1][j], p0);
                p0 += __shfl_xor(p0, 1);    // combine the two a-halves
                // softmax over 32 d's (no max-sub: |logits| small, f32-safe)
                const float e = __expf(p0);
                float ssum = e;
                ssum += __shfl_xor(ssum, 2);
                ssum += __shfl_xor(ssum, 4);
                ssum += __shfl_xor(ssum, 8);
                ssum += __shfl_xor(ssum, 16);
                ssum += __shfl_xor(ssum, 32);
                const float r = e * __builtin_amdgcn_rcpf(ssum);
                #pragma unroll
                for (int j = 0; j < 8; ++j) rV[j] = r * V[j];
            }

            // LDS accumulate: pre[b][q][lane] += rV  (race-free by stagger)
            float* pb = &pre[b * O_ + lane * 4];
            float4 p0 = *(float4*)pb;
            float4 p1 = *(float4*)(pb + 256);
            p0.x += rV[0]; p0.y += rV[1]; p0.z += rV[2]; p0.w += rV[3];
            p1.x += rV[4]; p1.y += rV[5]; p1.z += rV[6]; p1.w += rV[7];
            *(float4*)pb = p0;
            *(float4*)(pb + 256) = p1;
        }
        // bound inter-wave skew to <8 steps (collision distance)
        __builtin_amdgcn_sched_barrier(0);
        __builtin_amdgcn_s_barrier();
        __builtin_amdgcn_sched_barrier(0);
    }

    __syncthreads();                        // all accumulation visible

    // flush pre -> partial[ig][b][o]; wave flushes its own 8 b's
    #pragma unroll
    for (int bb = 0; bb < 8; ++bb) {
        const int b = wv * 8 + bb;
        const float* pb = &pre[b * O_ + lane * 4];
        const float4 q0 = *(const float4*)pb;
        const float4 q1 = *(const float4*)(pb + 256);
        float4* dst = (float4*)(partial + ((size_t)ig * B_ + b) * O_ + obase);
        dst[0] = q0;
        dst[1] = q1;
    }
}

// sum NG_ partials -> *scale + bias -> squash over A -> out.
// If prev!=null also emit outsum = out + prev (act0+act1 for PASS2's fold).
__global__ __launch_bounds__(256)
void reduce_squash(const float* __restrict__ partial, const float* __restrict__ bias,
                   float scale, const float* __restrict__ prev,
                   float* __restrict__ out, float* __restrict__ outsum)
{
    const int t  = threadIdx.x;
    const int g  = blockIdx.x * 32 + (t & 31);   // b*512 + o
    const int sl = t >> 5;                       // w-slice 0..7
    float s = 0.f;
    #pragma unroll 8
    for (int w = sl * 64; w < sl * 64 + 64; ++w)
        s += partial[(size_t)w * (B_ * O_) + g];
    __shared__ float red[256];
    red[t] = s;
    __syncthreads();
    if (t < 32) {
        float v = red[t];
        #pragma unroll
        for (int r = 1; r < 8; ++r) v += red[t + 32 * r];
        const float p = fmaf(v, scale, bias[g & (O_ - 1)]);
        float nn = p * p;
        nn += __shfl_xor(nn, 1);
        nn += __shfl_xor(nn, 2);
        nn += __shfl_xor(nn, 4);
        nn += __shfl_xor(nn, 8);
        const float a = p * sqrtf(nn) / (1.f + nn);
        out[g] = a;
        if (outsum) outsum[g] = a + prev[g];
    }
}

extern "C" void kernel_launch(void* const* d_in, const int* in_sizes, int n_in,
                              void* d_out, int out_size, void* d_ws, size_t ws_size,
                              hipStream_t stream) {
    const float* x    = (const float*)d_in[0];   // [32,2048,16]
    const float* W    = (const float*)d_in[1];   // [2048,16,512]
    const float* bias = (const float*)d_in[2];   // [512]
    float* out = (float*)d_out;                  // [32,512]

    float* partial = (float*)d_ws;                       // 512*32*512 f32 = 33.5 MB
    float* act0    = partial + (size_t)NG_ * B_ * O_;    // 64 KB
    float* act1    = act0 + B_ * O_;                     // 64 KB
    float* actsum  = act1 + B_ * O_;                     // 64 KB

    sweep_kernel<0><<<NG_, 256, 0, stream>>>(x, W, nullptr, partial);
    reduce_squash<<<512, 256, 0, stream>>>(partial, bias, 1.f / 32.f, nullptr, act0, nullptr);
    sweep_kernel<1><<<NG_, 256, 0, stream>>>(x, W, act0, partial);
    reduce_squash<<<512, 256, 0, stream>>>(partial, bias, 1.f, act0, act1, actsum);
    sweep_kernel<2><<<NG_, 256, 0, stream>>>(x, W, actsum, partial);
    reduce_squash<<<512, 256, 0, stream>>>(partial, bias, 1.f, nullptr, out, nullptr);
}